// Round 1
// baseline (14510.593 us; speedup 1.0000x reference)
//
#include <hip/hip_runtime.h>

#define Vv 25
#define Tt 14
#define Ee 64
#define Hh 128
#define Ll 32
#define Ccc 8
#define G3 384   // 3*H

// ---------------------------------------------------------------------------
// Kernel A: precompute token -> input-projection tables.
//   enc_tab[v][j] = b_ih_e[j] + sum_e emb_enc[v][e] * W_ih_e[j][e]      (j<384)
//   dec_tab[v][j] =            sum_e emb_dec[v][e] * W_ih_d[j][e]      (emb cols only)
// ---------------------------------------------------------------------------
extern "C" __global__ void __launch_bounds__(256)
cvae_tables(const float* __restrict__ emb_enc, const float* __restrict__ W_ih_e,
            const float* __restrict__ b_ih_e, const float* __restrict__ emb_dec,
            const float* __restrict__ W_ih_d, float* __restrict__ ws)
{
    int id = blockIdx.x * 256 + threadIdx.x;      // 0 .. 19199
    if (id >= 2 * Vv * G3) return;
    int half = id / (Vv * G3);
    int r = id % (Vv * G3);
    int v = r / G3, j = r % G3;
    if (half == 0) {
        float acc = b_ih_e[j];
        const float* e = emb_enc + v * Ee;
        const float* w = W_ih_e + j * Ee;
        #pragma unroll 4
        for (int k = 0; k < Ee; k++) acc += e[k] * w[k];
        ws[v * G3 + j] = acc;
    } else {
        float acc = 0.0f;
        const float* e = emb_dec + v * Ee;
        const float* w = W_ih_d + j * 104;        // row length E+L+C = 104
        #pragma unroll 4
        for (int k = 0; k < Ee; k++) acc += e[k] * w[k];
        ws[Vv * G3 + v * G3 + j] = acc;
    }
}

__device__ __forceinline__ float sigm(float x) { return 1.0f / (1.0f + __expf(-x)); }
__device__ __forceinline__ float tanh_f(float x) { return 1.0f - 2.0f / (1.0f + __expf(2.0f * x)); }

// ---------------------------------------------------------------------------
// Kernel B: fully fused CVAE forward. One block = 64 batch elements, 512 thr.
// LDS: h[k][b] (k-major so lane=b reads are 2-way/bank = free), ctx[40][b].
// Thread (b = tid&63, g = tid>>6 in 0..7) owns hidden rows j = g*16 + i.
// ---------------------------------------------------------------------------
extern "C" __global__ void __launch_bounds__(512, 2)
cvae_main(const int* __restrict__ x, const float* __restrict__ cin,
          const float* __restrict__ eps,
          const float* __restrict__ W_hh_e, const float* __restrict__ b_hh_e,
          const float* __restrict__ W_mu, const float* __restrict__ b_mu,
          const float* __restrict__ W_lv, const float* __restrict__ b_lv,
          const float* __restrict__ W_fch, const float* __restrict__ b_fch,
          const float* __restrict__ W_ih_d, const float* __restrict__ W_hh_d,
          const float* __restrict__ b_ih_d, const float* __restrict__ b_hh_d,
          const float* __restrict__ W_out, const float* __restrict__ b_out,
          const float* __restrict__ enc_tab, const float* __restrict__ dec_tab,
          float* __restrict__ out, int Btot)
{
    __shared__ float hbuf[Hh][64];
    __shared__ float ctx[Ll + Ccc][64];

    const int tid = threadIdx.x;
    const int b = tid & 63;
    const int g = tid >> 6;                       // 0..7, wave-uniform
    const int bg = blockIdx.x * 64 + b;
    const size_t MU_OFF = (size_t)Btot * 13 * Vv;
    const size_t LV_OFF = MU_OFF + (size_t)Btot * Ll;

    // stage condition c into ctx rows 32..39 (coalesced: tid == bb*8+cc)
    {
        int bb = tid >> 3, cc = tid & 7;          // 512 threads == 64*8 exactly
        ctx[Ll + cc][bb] = cin[((size_t)blockIdx.x * 64 + bb) * Ccc + cc];
    }
    #pragma unroll
    for (int i = 0; i < 16; i++) hbuf[g * 16 + i][b] = 0.0f;
    __syncthreads();

    float hnew[16];

    // ================= encoder GRU: 14 steps =================
    for (int t = 0; t < Tt; t++) {
        const int tok = x[(size_t)bg * Tt + t];
        const float* tab = enc_tab + tok * G3;
        float aR[16], aZ[16], aNi[16], aNh[16];
        #pragma unroll
        for (int i = 0; i < 16; i++) {
            int j = g * 16 + i;
            aR[i]  = tab[j]          + b_hh_e[j];
            aZ[i]  = tab[Hh + j]     + b_hh_e[Hh + j];
            aNi[i] = tab[2 * Hh + j];
            aNh[i] = b_hh_e[2 * Hh + j];
        }
        const float4* wb = (const float4*)W_hh_e;  // row j = 32 float4
        #pragma unroll 1
        for (int k4 = 0; k4 < 32; k4++) {
            float h0 = hbuf[4 * k4 + 0][b], h1 = hbuf[4 * k4 + 1][b],
                  h2 = hbuf[4 * k4 + 2][b], h3 = hbuf[4 * k4 + 3][b];
            #pragma unroll
            for (int i = 0; i < 16; i++) {
                int j = g * 16 + i;
                float4 wr = wb[j * 32 + k4];
                float4 wz = wb[(Hh + j) * 32 + k4];
                float4 wn = wb[(2 * Hh + j) * 32 + k4];
                aR[i]  += wr.x * h0 + wr.y * h1 + wr.z * h2 + wr.w * h3;
                aZ[i]  += wz.x * h0 + wz.y * h1 + wz.z * h2 + wz.w * h3;
                aNh[i] += wn.x * h0 + wn.y * h1 + wn.z * h2 + wn.w * h3;
            }
        }
        #pragma unroll
        for (int i = 0; i < 16; i++) {
            int j = g * 16 + i;
            float r  = sigm(aR[i]);
            float zg = sigm(aZ[i]);
            float n  = tanh_f(aNi[i] + r * aNh[i]);
            hnew[i] = (1.0f - zg) * n + zg * hbuf[j][b];
        }
        __syncthreads();                          // all reads of old h done
        #pragma unroll
        for (int i = 0; i < 16; i++) hbuf[g * 16 + i][b] = hnew[i];
        __syncthreads();
    }

    // ================= latent: mu / logvar / z =================
    #pragma unroll 1
    for (int ii = 0; ii < 4; ii++) {
        int l = g * 4 + ii;                       // 8 groups * 4 = 32 latents
        float am = b_mu[l], av = b_lv[l];
        const float* wm = W_mu + l * (Hh + Ccc);
        const float* wv = W_lv + l * (Hh + Ccc);
        #pragma unroll 4
        for (int k = 0; k < Hh; k++) {
            float hv = hbuf[k][b];
            am += hv * wm[k];
            av += hv * wv[k];
        }
        #pragma unroll
        for (int cc = 0; cc < Ccc; cc++) {
            float cv = ctx[Ll + cc][b];
            am += cv * wm[Hh + cc];
            av += cv * wv[Hh + cc];
        }
        out[MU_OFF + (size_t)bg * Ll + l] = am;
        out[LV_OFF + (size_t)bg * Ll + l] = av;
        float zz = am + eps[(size_t)bg * Ll + l] * __expf(0.5f * av);
        ctx[l][b] = zz;                           // ctx rows 0..31 = z
    }
    __syncthreads();

    // ================= h0 = context @ W_fch.T + b_fch =================
    #pragma unroll 1
    for (int i = 0; i < 16; i++) {
        int j = g * 16 + i;
        float acc = b_fch[j];
        const float* w = W_fch + j * (Ll + Ccc);
        #pragma unroll
        for (int k = 0; k < Ll + Ccc; k++) acc += ctx[k][b] * w[k];
        hbuf[j][b] = acc;                         // safe: barrier above ended all hbuf reads
    }
    __syncthreads();

    // ================= decoder GRU: 13 steps + fused vocab projection ======
    for (int t = 0; t < Tt - 1; t++) {
        const int tok = x[(size_t)bg * Tt + t];   // dec_in = x[:, :-1]
        const float* tab = dec_tab + tok * G3;
        float aR[16], aZ[16], aNi[16], aNh[16];
        #pragma unroll
        for (int i = 0; i < 16; i++) {
            int j = g * 16 + i;
            aR[i]  = tab[j]          + b_ih_d[j]          + b_hh_d[j];
            aZ[i]  = tab[Hh + j]     + b_ih_d[Hh + j]     + b_hh_d[Hh + j];
            aNi[i] = tab[2 * Hh + j] + b_ih_d[2 * Hh + j];
            aNh[i] = b_hh_d[2 * Hh + j];
        }
        const float4* wb = (const float4*)W_hh_d;
        #pragma unroll 1
        for (int k4 = 0; k4 < 32; k4++) {
            float h0 = hbuf[4 * k4 + 0][b], h1 = hbuf[4 * k4 + 1][b],
                  h2 = hbuf[4 * k4 + 2][b], h3 = hbuf[4 * k4 + 3][b];
            #pragma unroll
            for (int i = 0; i < 16; i++) {
                int j = g * 16 + i;
                float4 wr = wb[j * 32 + k4];
                float4 wz = wb[(Hh + j) * 32 + k4];
                float4 wn = wb[(2 * Hh + j) * 32 + k4];
                aR[i]  += wr.x * h0 + wr.y * h1 + wr.z * h2 + wr.w * h3;
                aZ[i]  += wz.x * h0 + wz.y * h1 + wz.z * h2 + wz.w * h3;
                aNh[i] += wn.x * h0 + wn.y * h1 + wn.z * h2 + wn.w * h3;
            }
        }
        // context contribution: cols 64..103 of W_ih_d (rows are 16B aligned: 104*4=416)
        #pragma unroll 1
        for (int k4 = 0; k4 < 10; k4++) {
            float c0 = ctx[4 * k4 + 0][b], c1 = ctx[4 * k4 + 1][b],
                  c2 = ctx[4 * k4 + 2][b], c3 = ctx[4 * k4 + 3][b];
            #pragma unroll
            for (int i = 0; i < 16; i++) {
                int j = g * 16 + i;
                float4 wr = ((const float4*)(W_ih_d + j * 104 + Ee))[k4];
                float4 wz = ((const float4*)(W_ih_d + (Hh + j) * 104 + Ee))[k4];
                float4 wn = ((const float4*)(W_ih_d + (2 * Hh + j) * 104 + Ee))[k4];
                aR[i]  += wr.x * c0 + wr.y * c1 + wr.z * c2 + wr.w * c3;
                aZ[i]  += wz.x * c0 + wz.y * c1 + wz.z * c2 + wz.w * c3;
                aNi[i] += wn.x * c0 + wn.y * c1 + wn.z * c2 + wn.w * c3;
            }
        }
        #pragma unroll
        for (int i = 0; i < 16; i++) {
            int j = g * 16 + i;
            float r  = sigm(aR[i]);
            float zg = sigm(aZ[i]);
            float n  = tanh_f(aNi[i] + r * aNh[i]);
            hnew[i] = (1.0f - zg) * n + zg * hbuf[j][b];
        }
        __syncthreads();
        #pragma unroll
        for (int i = 0; i < 16; i++) hbuf[g * 16 + i][b] = hnew[i];
        __syncthreads();

        // recon[b][t][v] = h_new . W_out[v] + b_out[v]; v = g + 8*ii covers 0..24
        float acc[4] = {0.0f, 0.0f, 0.0f, 0.0f};
        const float4* wo = (const float4*)W_out;
        #pragma unroll 1
        for (int k4 = 0; k4 < 32; k4++) {
            float h0 = hbuf[4 * k4 + 0][b], h1 = hbuf[4 * k4 + 1][b],
                  h2 = hbuf[4 * k4 + 2][b], h3 = hbuf[4 * k4 + 3][b];
            #pragma unroll
            for (int ii = 0; ii < 4; ii++) {
                int v = g + 8 * ii;
                if (v < Vv) {
                    float4 w = wo[v * 32 + k4];
                    acc[ii] += w.x * h0 + w.y * h1 + w.z * h2 + w.w * h3;
                }
            }
        }
        #pragma unroll
        for (int ii = 0; ii < 4; ii++) {
            int v = g + 8 * ii;
            if (v < Vv) out[((size_t)bg * 13 + t) * Vv + v] = acc[ii] + b_out[v];
        }
    }
}

extern "C" void kernel_launch(void* const* d_in, const int* in_sizes, int n_in,
                              void* d_out, int out_size, void* d_ws, size_t ws_size,
                              hipStream_t stream)
{
    const int*   x       = (const int*)d_in[0];
    const float* c       = (const float*)d_in[1];
    const float* eps     = (const float*)d_in[2];
    const float* emb_enc = (const float*)d_in[3];
    const float* W_ih_e  = (const float*)d_in[4];
    const float* W_hh_e  = (const float*)d_in[5];
    const float* b_ih_e  = (const float*)d_in[6];
    // d_in[7] = b_hh_e
    const float* b_hh_e  = (const float*)d_in[7];
    const float* W_mu    = (const float*)d_in[8];
    const float* b_mu    = (const float*)d_in[9];
    const float* W_lv    = (const float*)d_in[10];
    const float* b_lv    = (const float*)d_in[11];
    const float* emb_dec = (const float*)d_in[12];
    const float* W_fch   = (const float*)d_in[13];
    const float* b_fch   = (const float*)d_in[14];
    const float* W_ih_d  = (const float*)d_in[15];
    const float* W_hh_d  = (const float*)d_in[16];
    const float* b_ih_d  = (const float*)d_in[17];
    const float* b_hh_d  = (const float*)d_in[18];
    const float* W_out   = (const float*)d_in[19];
    const float* b_out   = (const float*)d_in[20];

    float* ws = (float*)d_ws;
    const int Btot = in_sizes[0] / Tt;            // 65536

    // 2*25*384 = 19200 table entries, 75 blocks * 256 threads exactly
    cvae_tables<<<75, 256, 0, stream>>>(emb_enc, W_ih_e, b_ih_e, emb_dec, W_ih_d, ws);

    cvae_main<<<Btot / 64, 512, 0, stream>>>(
        x, c, eps, W_hh_e, b_hh_e, W_mu, b_mu, W_lv, b_lv,
        W_fch, b_fch, W_ih_d, W_hh_d, b_ih_d, b_hh_d, W_out, b_out,
        ws, ws + Vv * G3, (float*)d_out, Btot);
}

// Round 3
// 681.106 us; speedup vs baseline: 21.3045x; 21.3045x over previous
//
#include <hip/hip_runtime.h>

typedef __bf16 bf16x8 __attribute__((ext_vector_type(8)));
typedef __bf16 bf16x4 __attribute__((ext_vector_type(4)));
typedef float  floatx4 __attribute__((ext_vector_type(4)));

#define Vv 25
#define Tt 14
#define Ee 64
#define Hh 128
#define Ll 32
#define Ccc 8
#define G3 384
#define TABP 392   // padded token-table row stride (bf16 elems)
#define HP   136   // padded h row stride (bf16 elems): 128+8
#define CXP  72    // padded ctx row stride (bf16 elems): 64+8

// ---------------------------------------------------------------------------
// Kernel A: token -> input-projection tables (f32, in ws).
//   enc_tab[v][j] = b_ih_e[j] + emb_enc[v]·W_ih_e[j]   (includes b_ih_e)
//   dec_tab[v][j] =            emb_dec[v]·W_ih_d[j][:64]  (no bias)
// ---------------------------------------------------------------------------
extern "C" __global__ void __launch_bounds__(256)
cvae_tables(const float* __restrict__ emb_enc, const float* __restrict__ W_ih_e,
            const float* __restrict__ b_ih_e, const float* __restrict__ emb_dec,
            const float* __restrict__ W_ih_d, float* __restrict__ ws)
{
    int id = blockIdx.x * 256 + threadIdx.x;
    if (id >= 2 * Vv * G3) return;
    int half = id / (Vv * G3);
    int r = id % (Vv * G3);
    int v = r / G3, j = r % G3;
    if (half == 0) {
        float acc = b_ih_e[j];
        const float* e = emb_enc + v * Ee;
        const float* w = W_ih_e + j * Ee;
        #pragma unroll 4
        for (int k = 0; k < Ee; k++) acc += e[k] * w[k];
        ws[v * G3 + j] = acc;
    } else {
        float acc = 0.0f;
        const float* e = emb_dec + v * Ee;
        const float* w = W_ih_d + j * 104;
        #pragma unroll 4
        for (int k = 0; k < Ee; k++) acc += e[k] * w[k];
        ws[Vv * G3 + v * G3 + j] = acc;
    }
}

__device__ __forceinline__ float rcp_f(float x) { return __builtin_amdgcn_rcpf(x); }
__device__ __forceinline__ float sigm(float x)  { return rcp_f(1.0f + __expf(-x)); }
__device__ __forceinline__ float tanhg(float x) { return 1.0f - 2.0f * rcp_f(1.0f + __expf(2.0f * x)); }

// ---------------------------------------------------------------------------
// Fused CVAE forward, MFMA version. 512 thr = 8 waves, 64 batch rows / block.
// GEMM as gh^T = W · h^T  (M=j rows of W, N=batch):
//   A-frag (W, stationary in regs): lane holds W[mt*16+(lane&15)][kb*32+q*8+jj]
//   B-frag (h, LDS bf16):           lane holds h[nt*16+(lane&15)][kb*32+q*8+jj]
//   C tile: col = lane&15 = batch, row = q*4+reg = j-local
// Wave w owns j in [16w,16w+16).
// LDS total: 17408 + 19600 + 9216 + 3584 = 49808 B (< 64 KiB static limit).
// ---------------------------------------------------------------------------
extern "C" __global__ void __launch_bounds__(512, 2)
cvae_mfma(const int* __restrict__ x, const float* __restrict__ cin,
          const float* __restrict__ eps,
          const float* __restrict__ W_hh_e, const float* __restrict__ b_hh_e,
          const float* __restrict__ W_mu, const float* __restrict__ b_mu,
          const float* __restrict__ W_lv, const float* __restrict__ b_lv,
          const float* __restrict__ W_fch, const float* __restrict__ b_fch,
          const float* __restrict__ W_ih_d, const float* __restrict__ W_hh_d,
          const float* __restrict__ b_ih_d, const float* __restrict__ b_hh_d,
          const float* __restrict__ W_out, const float* __restrict__ b_out,
          const float* __restrict__ tabs, float* __restrict__ out, int Btot)
{
    __shared__ __bf16 h_s[64 * HP];       // 17408 B
    __shared__ __bf16 tab_s[Vv * TABP];   // 19600 B
    __shared__ __bf16 ctx_s[64 * CXP];    //  9216 B
    __shared__ int    x_s[64 * Tt];       //  3584 B

    const int tid  = threadIdx.x;
    const int w    = tid >> 6;            // wave id 0..7 (wave-uniform)
    const int lane = tid & 63;
    const int li   = lane & 15;
    const int q    = lane >> 4;           // quad 0..3
    const int b0   = blockIdx.x * 64;
    const size_t MU_OFF = (size_t)Btot * 13 * Vv;
    const size_t LV_OFF = MU_OFF + (size_t)Btot * Ll;
    const floatx4 zf = {0.f, 0.f, 0.f, 0.f};

    // ---- stage tokens + enc_tab (bf16), zero h ----
    for (int i = tid; i < 64 * Tt; i += 512) x_s[i] = x[(size_t)b0 * Tt + i];
    for (int i = tid; i < Vv * G3; i += 512)
        tab_s[(i / G3) * TABP + (i % G3)] = (__bf16)tabs[i];
    for (int i = tid; i < 64 * HP; i += 512) h_s[i] = (__bf16)0.f;

    // ---- encoder W_hh A-frags (stationary) + b_hh ----
    bf16x8 aW[3][4];
    #pragma unroll
    for (int role = 0; role < 3; role++)
        #pragma unroll
        for (int kb = 0; kb < 4; kb++) {
            const float* p = W_hh_e + (role * Hh + w * 16 + li) * Hh + kb * 32 + q * 8;
            bf16x8 f;
            #pragma unroll
            for (int jj = 0; jj < 8; jj++) f[jj] = (__bf16)p[jj];
            aW[role][kb] = f;
        }
    float bhh[3][4];
    #pragma unroll
    for (int role = 0; role < 3; role++)
        #pragma unroll
        for (int r = 0; r < 4; r++) bhh[role][r] = b_hh_e[role * Hh + w * 16 + q * 4 + r];

    float hreg[4][4];
    #pragma unroll
    for (int nt = 0; nt < 4; nt++)
        #pragma unroll
        for (int r = 0; r < 4; r++) hreg[nt][r] = 0.f;

    __syncthreads();

    // ================= encoder GRU: 14 steps =================
    for (int t = 0; t < Tt; t++) {
        bf16x8 hf[4][4];
        #pragma unroll
        for (int nt = 0; nt < 4; nt++)
            #pragma unroll
            for (int kb = 0; kb < 4; kb++)
                hf[nt][kb] = *(const bf16x8*)&h_s[(nt * 16 + li) * HP + kb * 32 + q * 8];
        __syncthreads();                              // all h reads done

        floatx4 acc[3][4];
        #pragma unroll
        for (int role = 0; role < 3; role++)
            #pragma unroll
            for (int nt = 0; nt < 4; nt++) acc[role][nt] = zf;
        #pragma unroll
        for (int kb = 0; kb < 4; kb++)
            #pragma unroll
            for (int role = 0; role < 3; role++)
                #pragma unroll
                for (int nt = 0; nt < 4; nt++)
                    acc[role][nt] = __builtin_amdgcn_mfma_f32_16x16x32_bf16(
                        aW[role][kb], hf[nt][kb], acc[role][nt], 0, 0, 0);

        #pragma unroll
        for (int nt = 0; nt < 4; nt++) {
            int bl = nt * 16 + li;
            int tok = x_s[bl * Tt + t];
            const __bf16* tp = &tab_s[tok * TABP + w * 16 + q * 4];
            bf16x4 tR = *(const bf16x4*)(tp);
            bf16x4 tZ = *(const bf16x4*)(tp + Hh);
            bf16x4 tN = *(const bf16x4*)(tp + 2 * Hh);
            #pragma unroll
            for (int r = 0; r < 4; r++) {
                float rr = sigm(acc[0][nt][r] + (float)tR[r] + bhh[0][r]);
                float zz = sigm(acc[1][nt][r] + (float)tZ[r] + bhh[1][r]);
                float nn = tanhg((float)tN[r] + rr * (acc[2][nt][r] + bhh[2][r]));
                float h  = (1.f - zz) * nn + zz * hreg[nt][r];
                hreg[nt][r] = h;
                h_s[bl * HP + w * 16 + q * 4 + r] = (__bf16)h;
            }
        }
        __syncthreads();                              // h_new visible
    }

    // ================= latent + h0 + dec_tab staging =================
    {
        int b = tid & 63, g = w;
        size_t bg = (size_t)b0 + b;
        float cv[8];
        #pragma unroll
        for (int cc = 0; cc < 8; cc++) cv[cc] = cin[bg * Ccc + cc];
        ctx_s[b * CXP + Ll + g] = (__bf16)cv[g];
        #pragma unroll
        for (int k3 = 0; k3 < 3; k3++) ctx_s[b * CXP + 40 + g * 3 + k3] = (__bf16)0.f;

        float sm[4], sv[4];
        #pragma unroll
        for (int ii = 0; ii < 4; ii++) { sm[ii] = b_mu[g * 4 + ii]; sv[ii] = b_lv[g * 4 + ii]; }
        for (int k = 0; k < Hh; k++) {
            float hv = (float)h_s[b * HP + k];
            #pragma unroll
            for (int ii = 0; ii < 4; ii++) {
                sm[ii] += hv * W_mu[(g * 4 + ii) * 136 + k];
                sv[ii] += hv * W_lv[(g * 4 + ii) * 136 + k];
            }
        }
        #pragma unroll
        for (int cc = 0; cc < 8; cc++)
            #pragma unroll
            for (int ii = 0; ii < 4; ii++) {
                sm[ii] += cv[cc] * W_mu[(g * 4 + ii) * 136 + Hh + cc];
                sv[ii] += cv[cc] * W_lv[(g * 4 + ii) * 136 + Hh + cc];
            }
        #pragma unroll
        for (int ii = 0; ii < 4; ii++) {
            int l = g * 4 + ii;
            out[MU_OFF + bg * Ll + l] = sm[ii];
            out[LV_OFF + bg * Ll + l] = sv[ii];
            float zz = sm[ii] + eps[bg * Ll + l] * __expf(0.5f * sv[ii]);
            ctx_s[b * CXP + l] = (__bf16)zz;
        }
        __syncthreads();                              // ctx ready, h_s reads done

        // h0 = ctx·W_fch^T + b_fch  -> h_s (bf16)
        for (int i = 0; i < 16; i++) {
            int j = g * 16 + i;
            float s = b_fch[j];
            const float* wf = W_fch + j * 40;
            for (int k = 0; k < 40; k++) s += (float)ctx_s[b * CXP + k] * wf[k];
            h_s[b * HP + j] = (__bf16)s;
        }
        // dec_tab overwrites enc_tab
        for (int i = tid; i < Vv * G3; i += 512)
            tab_s[(i / G3) * TABP + (i % G3)] = (__bf16)tabs[Vv * G3 + i];
        __syncthreads();
    }

    // ---- decoder W_hh A-frags ----
    #pragma unroll
    for (int role = 0; role < 3; role++)
        #pragma unroll
        for (int kb = 0; kb < 4; kb++) {
            const float* p = W_hh_d + (role * Hh + w * 16 + li) * Hh + kb * 32 + q * 8;
            bf16x8 f;
            #pragma unroll
            for (int jj = 0; jj < 8; jj++) f[jj] = (__bf16)p[jj];
            aW[role][kb] = f;
        }

    // ---- t-invariant base = ctx·W_ihd_ctx (MFMA, K padded to 64) + biases ----
    floatx4 base[3][4];
    #pragma unroll
    for (int role = 0; role < 3; role++)
        #pragma unroll
        for (int nt = 0; nt < 4; nt++) base[role][nt] = zf;
    #pragma unroll
    for (int kb2 = 0; kb2 < 2; kb2++) {
        bf16x8 aC[3];
        #pragma unroll
        for (int role = 0; role < 3; role++) {
            int row = role * Hh + w * 16 + li;
            bf16x8 f;
            #pragma unroll
            for (int jj = 0; jj < 8; jj++) {
                int k = kb2 * 32 + q * 8 + jj;        // ctx k (0..63); valid < 40
                f[jj] = (k < 40) ? (__bf16)W_ih_d[row * 104 + Ee + k] : (__bf16)0.f;
            }
            aC[role] = f;
        }
        #pragma unroll
        for (int nt = 0; nt < 4; nt++) {
            bf16x8 cf = *(const bf16x8*)&ctx_s[(nt * 16 + li) * CXP + kb2 * 32 + q * 8];
            #pragma unroll
            for (int role = 0; role < 3; role++)
                base[role][nt] = __builtin_amdgcn_mfma_f32_16x16x32_bf16(aC[role], cf, base[role][nt], 0, 0, 0);
        }
    }
    float bhn[4];
    #pragma unroll
    for (int r = 0; r < 4; r++) {
        int j = w * 16 + q * 4 + r;
        float br = b_ih_d[j] + b_hh_d[j];
        float bz = b_ih_d[Hh + j] + b_hh_d[Hh + j];
        float bi = b_ih_d[2 * Hh + j];
        #pragma unroll
        for (int nt = 0; nt < 4; nt++) {
            base[0][nt][r] += br;
            base[1][nt][r] += bz;
            base[2][nt][r] += bi;
        }
        bhn[r] = b_hh_d[2 * Hh + j];
    }

    // ---- W_out frags: wave w -> tile (mt_o = w&1, nt_o = w>>1) ----
    const int mt_o = w & 1, nt_o = w >> 1;
    bf16x8 aO[4];
    #pragma unroll
    for (int kb = 0; kb < 4; kb++) {
        int row = mt_o * 16 + li;
        bf16x8 f;
        #pragma unroll
        for (int jj = 0; jj < 8; jj++)
            f[jj] = (row < Vv) ? (__bf16)W_out[row * Hh + kb * 32 + q * 8 + jj] : (__bf16)0.f;
        aO[kb] = f;
    }
    float bo[4];
    #pragma unroll
    for (int r = 0; r < 4; r++) {
        int v = mt_o * 16 + q * 4 + r;
        bo[r] = (v < Vv) ? b_out[v] : 0.f;
    }

    // h0 -> registers
    #pragma unroll
    for (int nt = 0; nt < 4; nt++)
        #pragma unroll
        for (int r = 0; r < 4; r++)
            hreg[nt][r] = (float)h_s[(nt * 16 + li) * HP + w * 16 + q * 4 + r];

    // ================= decoder GRU: 13 steps + fused vocab proj =============
    for (int t = 0; t < Tt - 1; t++) {
        bf16x8 hf[4][4];
        #pragma unroll
        for (int nt = 0; nt < 4; nt++)
            #pragma unroll
            for (int kb = 0; kb < 4; kb++)
                hf[nt][kb] = *(const bf16x8*)&h_s[(nt * 16 + li) * HP + kb * 32 + q * 8];
        __syncthreads();                              // all h reads done

        floatx4 acc[3][4];
        #pragma unroll
        for (int nt = 0; nt < 4; nt++) {
            acc[0][nt] = base[0][nt];
            acc[1][nt] = base[1][nt];
            acc[2][nt] = zf;                          // h·W_n part kept separate
        }
        #pragma unroll
        for (int kb = 0; kb < 4; kb++)
            #pragma unroll
            for (int role = 0; role < 3; role++)
                #pragma unroll
                for (int nt = 0; nt < 4; nt++)
                    acc[role][nt] = __builtin_amdgcn_mfma_f32_16x16x32_bf16(
                        aW[role][kb], hf[nt][kb], acc[role][nt], 0, 0, 0);

        #pragma unroll
        for (int nt = 0; nt < 4; nt++) {
            int bl = nt * 16 + li;
            int tok = x_s[bl * Tt + t];               // dec_in = x[:, :-1]
            const __bf16* tp = &tab_s[tok * TABP + w * 16 + q * 4];
            bf16x4 tR = *(const bf16x4*)(tp);
            bf16x4 tZ = *(const bf16x4*)(tp + Hh);
            bf16x4 tN = *(const bf16x4*)(tp + 2 * Hh);
            #pragma unroll
            for (int r = 0; r < 4; r++) {
                float rr = sigm(acc[0][nt][r] + (float)tR[r]);
                float zz = sigm(acc[1][nt][r] + (float)tZ[r]);
                float nn = tanhg(base[2][nt][r] + (float)tN[r] + rr * (acc[2][nt][r] + bhn[r]));
                float h  = (1.f - zz) * nn + zz * hreg[nt][r];
                hreg[nt][r] = h;
                h_s[bl * HP + w * 16 + q * 4 + r] = (__bf16)h;
            }
        }
        __syncthreads();                              // h_new visible

        // vocab projection: one 16x16 tile per wave
        bf16x8 of[4];
        #pragma unroll
        for (int kb = 0; kb < 4; kb++)
            of[kb] = *(const bf16x8*)&h_s[(nt_o * 16 + li) * HP + kb * 32 + q * 8];
        floatx4 po = zf;
        #pragma unroll
        for (int kb = 0; kb < 4; kb++)
            po = __builtin_amdgcn_mfma_f32_16x16x32_bf16(aO[kb], of[kb], po, 0, 0, 0);
        #pragma unroll
        for (int r = 0; r < 4; r++) {
            int v = mt_o * 16 + q * 4 + r;
            if (v < Vv)
                out[((size_t)(b0 + nt_o * 16 + li) * 13 + t) * Vv + v] = po[r] + bo[r];
        }
    }
}

extern "C" void kernel_launch(void* const* d_in, const int* in_sizes, int n_in,
                              void* d_out, int out_size, void* d_ws, size_t ws_size,
                              hipStream_t stream)
{
    const int*   x       = (const int*)d_in[0];
    const float* c       = (const float*)d_in[1];
    const float* eps     = (const float*)d_in[2];
    const float* emb_enc = (const float*)d_in[3];
    const float* W_ih_e  = (const float*)d_in[4];
    const float* W_hh_e  = (const float*)d_in[5];
    const float* b_ih_e  = (const float*)d_in[6];
    const float* b_hh_e  = (const float*)d_in[7];
    const float* W_mu    = (const float*)d_in[8];
    const float* b_mu    = (const float*)d_in[9];
    const float* W_lv    = (const float*)d_in[10];
    const float* b_lv    = (const float*)d_in[11];
    const float* emb_dec = (const float*)d_in[12];
    const float* W_fch   = (const float*)d_in[13];
    const float* b_fch   = (const float*)d_in[14];
    const float* W_ih_d  = (const float*)d_in[15];
    const float* W_hh_d  = (const float*)d_in[16];
    const float* b_ih_d  = (const float*)d_in[17];
    const float* b_hh_d  = (const float*)d_in[18];
    const float* W_out   = (const float*)d_in[19];
    const float* b_out   = (const float*)d_in[20];

    float* ws = (float*)d_ws;
    const int Btot = in_sizes[0] / Tt;

    cvae_tables<<<75, 256, 0, stream>>>(emb_enc, W_ih_e, b_ih_e, emb_dec, W_ih_d, ws);

    cvae_mfma<<<Btot / 64, 512, 0, stream>>>(
        x, c, eps, W_hh_e, b_hh_e, W_mu, b_mu, W_lv, b_lv,
        W_fch, b_fch, W_ih_d, W_hh_d, b_ih_d, b_hh_d, W_out, b_out,
        ws, (float*)d_out, Btot);
}